// Round 18
// baseline (184.864 us; speedup 1.0000x reference)
//
#include <hip/hip_runtime.h>
#include <hip/hip_bf16.h>

typedef short short8 __attribute__((ext_vector_type(8)));
typedef short short4v __attribute__((ext_vector_type(4)));
typedef float f32x4 __attribute__((ext_vector_type(4)));
typedef unsigned int uint2v __attribute__((ext_vector_type(2)));

#define HID 96
#define WNUM 1664
#define NA_DIM 56
#define OUT_DIM 80
#define EPB 64
#define NT_TOT 104   // 1664/16
#define CHW 208      // cols per chunk
#define NCH 8
#define NTC 13       // n-tiles per chunk
#define APAD 104     // padded bf16 row stride for A/h staging (bank spread)

#define N0f 0.158113883f      // 1/sqrt(40)
#define INV_S3 0.5773502692f  // 1/sqrt(3)
#define C_OUT1E 0.25f         // (1/sqrt(2))*(1/sqrt(8))

// prep-time (cold path) convert, RTNE
__device__ __forceinline__ unsigned short f2bf(float x) {
  unsigned u = __builtin_bit_cast(unsigned, x);
  u += 0x7FFFu + ((u >> 16) & 1u);
  return (unsigned short)(u >> 16);
}
// hot-path convert: native HW v_cvt_bf16_f32 (RTNE, pairs pack to v_cvt_pk)
__device__ __forceinline__ unsigned short f2bf_hw(float x) {
  __hip_bfloat16 b = __float2bfloat16(x);
  return __builtin_bit_cast(unsigned short, b);
}
__device__ __forceinline__ float bf2f(unsigned short x) {
  unsigned u = ((unsigned)x) << 16;
  return __builtin_bit_cast(float, u);
}

// packed bf16 dot2: acc += w.lo*x.lo + w.hi*x.hi  (w,x = 2 bf16 in a u32)
#if __has_builtin(__builtin_amdgcn_fdot2_f32_bf16)
typedef __bf16 bf16x2 __attribute__((ext_vector_type(2)));
#define DOT2(acc, w, x) \
  acc = __builtin_amdgcn_fdot2_f32_bf16(__builtin_bit_cast(bf16x2, (unsigned)(w)), \
                                        __builtin_bit_cast(bf16x2, (unsigned)(x)), (acc), false)
#else
#define DOT2(acc, w, x) do { \
  unsigned _w = (w), _x = (x); \
  acc = fmaf(__builtin_bit_cast(float, _w << 16), __builtin_bit_cast(float, _x << 16), acc); \
  acc = fmaf(__builtin_bit_cast(float, _w & 0xFFFF0000u), __builtin_bit_cast(float, _x & 0xFFFF0000u), acc); \
} while (0)
#endif

// column permutation: new col J -> original W2 col
__device__ __forceinline__ int perm_col(int J) {
  int c = J / CHW, l = J - (J / CHW) * CHW;
  if (l < 128) { int vp = l >> 5, u = l & 31; return u * 32 + 4 * c + vp; }          // w1
  if (l < 160) { int u = l - 128; return 1024 + u * 8 + c; }                          // w2
  if (l < 168) { int u = l - 160; return 1280 + u * 8 + c; }                          // w3
  if (l < 200) { int q = l - 168; int vp = q >> 3, u = q & 7; return 1344 + u * 32 + 4 * c + vp; } // w4
  { int u = l - 200; return 1600 + u * 8 + c; }                                       // w5
}

// ---------------- counting sort of edges by edge_src ----------------
__global__ __launch_bounds__(256) void hist_kernel(
    const int* __restrict__ edge_src, int* __restrict__ hist, int E) {
  int e = blockIdx.x * 256 + threadIdx.x;
  if (e < E) atomicAdd(&hist[edge_src[e]], 1);
}

__global__ __launch_bounds__(256) void scan1_kernel(
    const int* __restrict__ hist, int* __restrict__ excl,
    int* __restrict__ bsum, int n) {
  __shared__ int s[256];
  int t = threadIdx.x, i = blockIdx.x * 256 + t;
  int v = (i < n) ? hist[i] : 0;
  s[t] = v;
  __syncthreads();
  #pragma unroll
  for (int off = 1; off < 256; off <<= 1) {
    int tv = (t >= off) ? s[t - off] : 0;
    __syncthreads();
    s[t] += tv;
    __syncthreads();
  }
  if (i < n) excl[i] = s[t] - v;
  if (t == 255) bsum[blockIdx.x] = s[255];
}

// merged scan2+scan3: each block locally scans the (<=256) block sums
__global__ __launch_bounds__(256) void scan23_kernel(
    const int* __restrict__ excl, const int* __restrict__ bsum,
    int* __restrict__ start, int* __restrict__ cur, int n, int nb) {
  __shared__ int s[256];
  int t = threadIdx.x;
  int v = (t < nb) ? bsum[t] : 0;
  s[t] = v;
  __syncthreads();
  #pragma unroll
  for (int off = 1; off < 256; off <<= 1) {
    int tv = (t >= off) ? s[t - off] : 0;
    __syncthreads();
    s[t] += tv;
    __syncthreads();
  }
  int add = (blockIdx.x > 0) ? s[blockIdx.x - 1] : 0;  // exclusive prefix of bsum
  int i = blockIdx.x * 256 + t;
  if (i < n) {
    int val = excl[i] + add;
    start[i] = val;
    cur[i] = val;
  }
}

// ---------------- weight prep (bf16 MFMA fragments) + hist zero ----------------
__global__ __launch_bounds__(256) void prep_kernel(
    const float* __restrict__ W2, const float* __restrict__ W1,
    const float* __restrict__ b2, unsigned short* __restrict__ W2p,
    unsigned short* __restrict__ W1p, float* __restrict__ b2p,
    int* __restrict__ hist, int nhist)
{
  int gid = blockIdx.x * 256 + threadIdx.x;
  if (gid < nhist) hist[gid] = 0;       // folded hist-zero (prep runs before hist)
  const int NW2 = NT_TOT * 3 * 64;
  const int NW1 = 18 * 64;
  if (gid < NW2) {
    int tile = gid >> 6, ln = gid & 63;
    int nt = tile / 3, s = tile - nt * 3;
    int J = nt * 16 + (ln & 15);
    int jo = perm_col(J);
    int kbase = s * 32 + ((ln >> 4) << 3);
    #pragma unroll
    for (int j = 0; j < 8; ++j)
      W2p[(size_t)gid * 8 + j] = f2bf(W2[(kbase + j) * WNUM + jo]);
  } else if (gid < NW2 + NW1) {
    int g = gid - NW2;
    int tile = g >> 6, ln = g & 63;
    int nt = tile / 3, s = tile - nt * 3;
    int col = nt * 16 + (ln & 15);
    int kbase = s * 32 + ((ln >> 4) << 3);
    #pragma unroll
    for (int j = 0; j < 8; ++j)
      W1p[(size_t)g * 8 + j] = f2bf(W1[(kbase + j) * HID + col]);
  } else if (gid < NW2 + NW1 + WNUM) {
    int J = gid - (NW2 + NW1);
    b2p[J] = b2[perm_col(J)];
  }
}

// K2: fused  h = relu(A@W1+b1) -> w = h@W2+b2 (MFMA, swapped operands)
//     chunk pipeline: prefetch(ch+1)->regs | TP(ch) | MFMA+store(ch+1) | barrier
//     NOTE: (512,2) bound: 2-blocks/CU residency is LDS-bound; VGPR only needs
//     <=128. (512,4) caps VGPR at 64 and risks catastrophic spill (R7/R10).
__global__ __launch_bounds__(512, 2) void fused_mfma(
    const float* __restrict__ edge_attr, const unsigned short* __restrict__ W1p,
    const float* __restrict__ b1, const unsigned short* __restrict__ W2p,
    const float* __restrict__ b2p, const float* __restrict__ node_attr,
    const float* __restrict__ edge_sh, const int* __restrict__ edge_src,
    const int* __restrict__ edge_dst, int* __restrict__ cur,
    unsigned short* __restrict__ tpg)
{
  __shared__ __align__(16) unsigned short ws[2][EPB][212];  // 54.3 KB dbuf (bf16)
  __shared__ __align__(8) unsigned short x0h[EPB][32];      // x0, packed bf16
  __shared__ __align__(8) unsigned short x1h[EPB][3][8];    // x1[m][u], packed bf16
  __shared__ __align__(8) unsigned short dsuh[EPB][8];      // x1.sh1, packed bf16
  __shared__ __align__(8) unsigned short crsh[EPB][3][8];   // cross, packed bf16
  __shared__ float x1s[EPB][3][8];
  __shared__ float sh1s[EPB][3];
  __shared__ float s0s[EPB];
  __shared__ int   dsts[EPB];
  __shared__ int   poss[EPB];

  // prologue-only aliases inside the (not-yet-used) ws double buffer:
  unsigned short* As = (unsigned short*)ws;        // [EPB][APAD] bf16 edge_attr
  unsigned short* hB = As + EPB * APAD;            // [EPB][APAD] bf16 h

  const int tid = threadIdx.x;
  const int e0 = blockIdx.x * EPB;

  if (tid < EPB) {
    dsts[tid] = edge_dst[e0 + tid];
    s0s[tid] = edge_sh[(size_t)(e0 + tid) * 4];
    poss[tid] = atomicAdd(&cur[edge_src[e0 + tid]], 1);  // inline scatter
  }
  if (tid >= 128 && tid < 128 + EPB * 3) {
    int i = tid - 128, e = i / 3, m = i - e * 3;
    sh1s[e][m] = edge_sh[(size_t)(e0 + e) * 4 + 1 + m];
  }
  __syncthreads();

  // stage node_attr -> x arrays ; edge_attr -> As (bf16)
  for (int idx = tid; idx < EPB * NA_DIM; idx += 512) {
    int e = idx / NA_DIM, c = idx - e * NA_DIM;
    float v = node_attr[(size_t)dsts[e] * NA_DIM + c];
    if (c < 32) x0h[e][c] = f2bf_hw(v);
    else { int q = c - 32; x1s[e][q % 3][q / 3] = v; x1h[e][q % 3][q / 3] = f2bf_hw(v); }
  }
  for (int idx = tid; idx < EPB * (HID / 4); idx += 512) {
    int e = idx / (HID / 4), c4 = (idx - e * (HID / 4)) * 4;
    f32x4 v = *(const f32x4*)&edge_attr[(size_t)(e0 + e) * HID + c4];
    unsigned short* d = &As[e * APAD + c4];
    d[0] = f2bf_hw(v[0]); d[1] = f2bf_hw(v[1]); d[2] = f2bf_hw(v[2]); d[3] = f2bf_hw(v[3]);
  }
  __syncthreads();

  { // per-(e,u) derived quantities; 512 = 64*8 exact
    int e = tid >> 3, u = tid & 7;
    float a0 = x1s[e][0][u], a1 = x1s[e][1][u], a2 = x1s[e][2][u];
    float b0 = sh1s[e][0], b1v = sh1s[e][1], b2v = sh1s[e][2];
    dsuh[e][u] = f2bf_hw(a0 * b0 + a1 * b1v + a2 * b2v);
    crsh[e][0][u] = f2bf_hw(a1 * b2v - a2 * b1v);
    crsh[e][1][u] = f2bf_hw(a2 * b0 - a0 * b2v);
    crsh[e][2][u] = f2bf_hw(a0 * b1v - a1 * b0);
  }

  const int ln = tid & 63, wv = tid >> 6;
  const int c16 = ln & 15, q4 = (ln >> 4) << 2, k8 = (ln >> 4) << 3;

  // in-kernel GEMM1 (swapped): acc[r] = h[edge=c16][ntile*16+q4+r] -> b64 write
  #pragma unroll
  for (int t = 0; t < 3; ++t) {
    int tt_ = wv * 3 + t;
    int mtile = tt_ / 6, ntile = tt_ - mtile * 6;
    short8 aA[3];
    #pragma unroll
    for (int s = 0; s < 3; ++s)
      aA[s] = *(const short8*)&As[(mtile * 16 + c16) * APAD + s * 32 + k8];
    f32x4 acc = {0.f, 0.f, 0.f, 0.f};
    #pragma unroll
    for (int s = 0; s < 3; ++s) {
      short8 bfr = *(const short8*)(W1p + ((size_t)(ntile * 3 + s) * 64 + ln) * 8);
      acc = __builtin_amdgcn_mfma_f32_16x16x32_bf16(bfr, aA[s], acc, 0, 0, 0);
    }
    f32x4 bb = *(const f32x4*)&b1[ntile * 16 + q4];
    short4v o;
    #pragma unroll
    for (int r = 0; r < 4; ++r)
      o[r] = (short)f2bf_hw(fmaxf(acc[r] + bb[r], 0.f));
    *(short4v*)&hB[(mtile * 16 + c16) * APAD + ntile * 16 + q4] = o;
  }
  __syncthreads();

  short8 af[4][3];
  #pragma unroll
  for (int mt = 0; mt < 4; ++mt)
    #pragma unroll
    for (int s = 0; s < 3; ++s)
      af[mt][s] = *(const short8*)&hB[(mt * 16 + c16) * APAD + s * 32 + k8];
  __syncthreads();  // af in regs; ws free for chunk buffering

  // --- hoist per-edge TP operands into registers (reused all 8 chunks) ---
  const int e = tid >> 3, tt = tid & 7;
  uint2v x0r[8], aux0, aux1;   // role-dependent payload, ~20 VGPRs
  if (tt < 7) {
    #pragma unroll
    for (int i = 0; i < 8; ++i) x0r[i] = *(const uint2v*)&x0h[e][i * 4];
    if (tt < 4) {
      aux0 = *(const uint2v*)&dsuh[e][0];
      aux1 = *(const uint2v*)&dsuh[e][4];
    } else {
      aux0 = *(const uint2v*)&x1h[e][tt - 4][0];
      aux1 = *(const uint2v*)&x1h[e][tt - 4][4];
    }
  } else {
    #pragma unroll
    for (int m = 0; m < 3; ++m) {
      x0r[2 * m]     = *(const uint2v*)&crsh[e][m][0];
      x0r[2 * m + 1] = *(const uint2v*)&crsh[e][m][4];
    }
  }

  // chunk-invariant addressing (swapped layout: wave owns w-col tiles wv, wv+8)
  const int l0m = wv * 16 + q4;                  // tile0 col base (l), 4-aligned
  const int pc0m = (l0m & 96) | ((l0m + ((l0m >> 5) << 2)) & 31);  // w1 swizzle (4-run safe)
  const unsigned short* w2a = W2p + ((size_t)(wv * 3) * 64 + ln) * 8;          // tile0
  const unsigned short* w2b = W2p + ((size_t)((wv + 8) * 3) * 64 + ln) * 8;    // tile1
  const size_t CSTRIDE = (size_t)NTC * 3 * 64 * 8;   // W2p u16 per chunk
  const bool has1 = wv < (NTC - 8);

  // pipeline registers: W2 fragments + biases for the in-flight chunk
  short8 pbf0[3], pbf1[3];
  f32x4 pbb0 = {0.f, 0.f, 0.f, 0.f}, pbb1 = {0.f, 0.f, 0.f, 0.f};

  auto prefetch = [&](int cc) {  // global loads -> regs; no wait forced here
    const size_t cb = (size_t)cc * CSTRIDE;
    #pragma unroll
    for (int s = 0; s < 3; ++s)
      pbf0[s] = *(const short8*)(w2a + cb + (size_t)s * 64 * 8);
    pbb0 = *(const f32x4*)&b2p[cc * CHW + l0m];
    if (has1) {
      #pragma unroll
      for (int s = 0; s < 3; ++s)
        pbf1[s] = *(const short8*)(w2b + cb + (size_t)s * 64 * 8);
      pbb1 = *(const f32x4*)&b2p[cc * CHW + 128 + l0m];
    }
  };
  auto mfma_store = [&](unsigned short (*wsd)[212]) {  // consume prefetched regs
    {
      f32x4 acc[4];
      #pragma unroll
      for (int et = 0; et < 4; ++et) acc[et] = (f32x4){0.f, 0.f, 0.f, 0.f};
      #pragma unroll
      for (int s = 0; s < 3; ++s)
        #pragma unroll
        for (int et = 0; et < 4; ++et)
          acc[et] = __builtin_amdgcn_mfma_f32_16x16x32_bf16(pbf0[s], af[et][s], acc[et], 0, 0, 0);
      #pragma unroll
      for (int et = 0; et < 4; ++et) {
        short4v o;
        #pragma unroll
        for (int r = 0; r < 4; ++r)
          o[r] = (short)f2bf_hw(acc[et][r] + pbb0[r]);
        *(short4v*)&wsd[et * 16 + c16][pc0m] = o;
      }
    }
    if (has1) {
      f32x4 acc[4];
      #pragma unroll
      for (int et = 0; et < 4; ++et) acc[et] = (f32x4){0.f, 0.f, 0.f, 0.f};
      #pragma unroll
      for (int s = 0; s < 3; ++s)
        #pragma unroll
        for (int et = 0; et < 4; ++et)
          acc[et] = __builtin_amdgcn_mfma_f32_16x16x32_bf16(pbf1[s], af[et][s], acc[et], 0, 0, 0);
      #pragma unroll
      for (int et = 0; et < 4; ++et) {
        short4v o;
        #pragma unroll
        for (int r = 0; r < 4; ++r)
          o[r] = (short)f2bf_hw(acc[et][r] + pbb1[r]);
        *(short4v*)&wsd[et * 16 + c16][128 + l0m] = o;
      }
    }
  };

  prefetch(0);
  mfma_store(ws[0]);
  __syncthreads();

  const float s0 = s0s[e];
  unsigned short* tpr = tpg + (size_t)poss[e] * OUT_DIM;   // sorted-position row

  for (int ch = 0; ch < NCH; ++ch) {
    if (ch < NCH - 1) prefetch(ch + 1);      // loads fly during TP below
    __builtin_amdgcn_sched_barrier(0);       // loads issued before TP

    const unsigned short (*wsr)[212] = ws[ch & 1];
    if (tt < 4) {
      float c0 = 0.f, c1 = 0.f, c2 = 0.f, c3 = 0.f;   // 4 ILP chains
      #pragma unroll
      for (int u0 = 0; u0 < 32; u0 += 8) {
        int pu  = (u0 + (tt << 2)) & 31;       // swizzled LDS col of logical u0
        int pu2 = (u0 + 4 + (tt << 2)) & 31;
        uint2v wq  = *(const uint2v*)&wsr[e][(tt << 5) + pu];
        uint2v wq2 = *(const uint2v*)&wsr[e][(tt << 5) + pu2];
        uint2v xq  = x0r[u0 >> 2];
        uint2v xq2 = x0r[(u0 >> 2) + 1];
        DOT2(c0, wq[0], xq[0]);
        DOT2(c1, wq[1], xq[1]);
        DOT2(c2, wq2[0], xq2[0]);
        DOT2(c3, wq2[1], xq2[1]);
      }
      float d0 = 0.f, d1 = 0.f;
      {
        uint2v wq  = *(const uint2v*)&wsr[e][168 + (tt << 3)];
        uint2v wq2 = *(const uint2v*)&wsr[e][168 + (tt << 3) + 4];
        DOT2(d0, wq[0], aux0[0]);
        DOT2(d1, wq[1], aux0[1]);
        DOT2(d0, wq2[0], aux1[0]);
        DOT2(d1, wq2[1], aux1[1]);
      }
      float sum1 = (c0 + c1) + (c2 + c3);
      tpr[4 * ch + tt] = f2bf_hw(N0f * (s0 * sum1 + INV_S3 * (d0 + d1)));
    } else if (tt < 7) {
      const int m = tt - 4;
      float c0 = 0.f, c1 = 0.f, c2 = 0.f, c3 = 0.f;
      #pragma unroll
      for (int u0 = 0; u0 < 32; u0 += 8) {
        uint2v wq  = *(const uint2v*)&wsr[e][128 + u0];
        uint2v wq2 = *(const uint2v*)&wsr[e][128 + u0 + 4];
        uint2v xq  = x0r[u0 >> 2];
        uint2v xq2 = x0r[(u0 >> 2) + 1];
        DOT2(c0, wq[0], xq[0]);
        DOT2(c1, wq[1], xq[1]);
        DOT2(c2, wq2[0], xq2[0]);
        DOT2(c3, wq2[1], xq2[1]);
      }
      float d0 = 0.f, d1 = 0.f;
      {
        uint2v wq  = *(const uint2v*)&wsr[e][160];
        uint2v wq2 = *(const uint2v*)&wsr[e][164];
        DOT2(d0, wq[0], aux0[0]);
        DOT2(d1, wq[1], aux0[1]);
        DOT2(d0, wq2[0], aux1[0]);
        DOT2(d1, wq2[1], aux1[1]);
      }
      float sum1 = (c0 + c1) + (c2 + c3);
      tpr[32 + ch * 3 + m] = f2bf_hw(N0f * (sh1s[e][m] * sum1 + s0 * (d0 + d1)));
    } else {
      uint2v wq  = *(const uint2v*)&wsr[e][200];
      uint2v wq2 = *(const uint2v*)&wsr[e][204];
      #pragma unroll
      for (int m = 0; m < 3; ++m) {
        float d0 = 0.f, d1 = 0.f;
        DOT2(d0, wq[0], x0r[2 * m][0]);
        DOT2(d1, wq[1], x0r[2 * m][1]);
        DOT2(d0, wq2[0], x0r[2 * m + 1][0]);
        DOT2(d1, wq2[1], x0r[2 * m + 1][1]);
        tpr[56 + ch * 3 + m] = f2bf_hw(C_OUT1E * (d0 + d1));
      }
    }

    __builtin_amdgcn_sched_barrier(0);       // TP fully issued before MFMA waits
    if (ch < NCH - 1) mfma_store(ws[(ch + 1) & 1]);  // other buffer: no WAR
    __syncthreads();  // ws[(ch+1)&1] complete, ws[ch&1] free for reuse
  }
}

// K3: per-node mean; tp rows are src-sorted (bf16) -> 2 bf16/thread streaming
__global__ __launch_bounds__(256) void gather_kernel(
    const unsigned short* __restrict__ tp, const int* __restrict__ start,
    const int* __restrict__ hist, float* __restrict__ out, int total2)
{
  int idx = blockIdx.x * 256 + threadIdx.x;
  if (idx >= total2) return;
  int node = idx / (OUT_DIM / 2), o2 = idx - node * (OUT_DIM / 2);
  int s = start[node], c = hist[node];
  float sa = 0.f, sb = 0.f;
  for (int i = 0; i < c; ++i) {
    unsigned v = *(const unsigned*)&tp[(size_t)(s + i) * OUT_DIM + o2 * 2];
    sa += bf2f((unsigned short)(v & 0xFFFF));
    sb += bf2f((unsigned short)(v >> 16));
  }
  float inv = 1.0f / (float)(c > 0 ? c : 1);
  out[(size_t)node * OUT_DIM + o2 * 2]     = sa * inv;
  out[(size_t)node * OUT_DIM + o2 * 2 + 1] = sb * inv;
}

extern "C" void kernel_launch(void* const* d_in, const int* in_sizes, int n_in,
                              void* d_out, int out_size, void* d_ws, size_t ws_size,
                              hipStream_t stream) {
  const float* node_attr = (const float*)d_in[0];
  const float* edge_attr = (const float*)d_in[1];
  const float* edge_sh   = (const float*)d_in[2];
  const float* W1        = (const float*)d_in[3];
  const float* b1        = (const float*)d_in[4];
  const float* W2        = (const float*)d_in[5];
  const float* b2        = (const float*)d_in[6];
  const int*   edge_src  = (const int*)d_in[7];
  const int*   edge_dst  = (const int*)d_in[8];
  float* out = (float*)d_out;

  const int E = in_sizes[7];
  const int N = in_sizes[0] / NA_DIM;

  char* wsb = (char*)d_ws;
  int*   hist  = (int*)(wsb + 0x000000);          // 40000 ints
  int*   excl  = (int*)(wsb + 0x040000);
  int*   start = (int*)(wsb + 0x080000);
  int*   cur   = (int*)(wsb + 0x0C0000);
  int*   bsum  = (int*)(wsb + 0x100000);          // 256 ints
  unsigned short* W2p = (unsigned short*)(wsb + 0x200000);   // 320 KB
  unsigned short* W1p = (unsigned short*)(wsb + 0x280000);
  float*          b2p = (float*)(wsb + 0x2C0000);
  unsigned short* tpg = (unsigned short*)(wsb + 0x1C00000);  // 19.2 MB (bf16)

  const int NB = (N + 255) / 256;  // 157

  // prep also zeros hist (grid sized to cover max(prep_total, N))
  const int prep_total = NT_TOT * 3 * 64 + 18 * 64 + WNUM;
  const int prep_grid = ((prep_total > N ? prep_total : N) + 255) / 256;
  prep_kernel<<<prep_grid, 256, 0, stream>>>(W2, W1, b2, W2p, W1p, b2p, hist, N);

  hist_kernel<<<(E + 255) / 256, 256, 0, stream>>>(edge_src, hist, E);
  scan1_kernel<<<NB, 256, 0, stream>>>(hist, excl, bsum, N);
  scan23_kernel<<<NB, 256, 0, stream>>>(excl, bsum, start, cur, N, NB);

  fused_mfma<<<E / EPB, 512, 0, stream>>>(edge_attr, W1p, b1, W2p, b2p,
                                          node_attr, edge_sh, edge_src, edge_dst,
                                          cur, tpg);
  gather_kernel<<<(N * (OUT_DIM / 2) + 255) / 256, 256, 0, stream>>>(
      tpg, start, hist, out, N * (OUT_DIM / 2));
}

// Round 19
// 140.090 us; speedup vs baseline: 1.3196x; 1.3196x over previous
//
#include <hip/hip_runtime.h>
#include <hip/hip_bf16.h>

typedef short short8 __attribute__((ext_vector_type(8)));
typedef short short4v __attribute__((ext_vector_type(4)));
typedef float f32x4 __attribute__((ext_vector_type(4)));
typedef unsigned int uint2v __attribute__((ext_vector_type(2)));

#define HID 96
#define WNUM 1664
#define NA_DIM 56
#define OUT_DIM 80
#define EPB 64
#define NT_TOT 104   // 1664/16
#define CHW 208      // cols per chunk
#define NCH 8
#define NTC 13       // n-tiles per chunk
#define APAD 104     // padded bf16 row stride for A/h staging (bank spread)

#define N0f 0.158113883f      // 1/sqrt(40)
#define INV_S3 0.5773502692f  // 1/sqrt(3)
#define C_OUT1E 0.25f         // (1/sqrt(2))*(1/sqrt(8))

// prep-time (cold path) convert, RTNE
__device__ __forceinline__ unsigned short f2bf(float x) {
  unsigned u = __builtin_bit_cast(unsigned, x);
  u += 0x7FFFu + ((u >> 16) & 1u);
  return (unsigned short)(u >> 16);
}
// hot-path convert: native HW v_cvt_bf16_f32 (RTNE, pairs pack to v_cvt_pk)
__device__ __forceinline__ unsigned short f2bf_hw(float x) {
  __hip_bfloat16 b = __float2bfloat16(x);
  return __builtin_bit_cast(unsigned short, b);
}
__device__ __forceinline__ float bf2f(unsigned short x) {
  unsigned u = ((unsigned)x) << 16;
  return __builtin_bit_cast(float, u);
}

// packed bf16 dot2: acc += w.lo*x.lo + w.hi*x.hi  (w,x = 2 bf16 in a u32)
#if __has_builtin(__builtin_amdgcn_fdot2_f32_bf16)
typedef __bf16 bf16x2 __attribute__((ext_vector_type(2)));
#define DOT2(acc, w, x) \
  acc = __builtin_amdgcn_fdot2_f32_bf16(__builtin_bit_cast(bf16x2, (unsigned)(w)), \
                                        __builtin_bit_cast(bf16x2, (unsigned)(x)), (acc), false)
#else
#define DOT2(acc, w, x) do { \
  unsigned _w = (w), _x = (x); \
  acc = fmaf(__builtin_bit_cast(float, _w << 16), __builtin_bit_cast(float, _x << 16), acc); \
  acc = fmaf(__builtin_bit_cast(float, _w & 0xFFFF0000u), __builtin_bit_cast(float, _x & 0xFFFF0000u), acc); \
} while (0)
#endif

// column permutation: new col J -> original W2 col
__device__ __forceinline__ int perm_col(int J) {
  int c = J / CHW, l = J - (J / CHW) * CHW;
  if (l < 128) { int vp = l >> 5, u = l & 31; return u * 32 + 4 * c + vp; }          // w1
  if (l < 160) { int u = l - 128; return 1024 + u * 8 + c; }                          // w2
  if (l < 168) { int u = l - 160; return 1280 + u * 8 + c; }                          // w3
  if (l < 200) { int q = l - 168; int vp = q >> 3, u = q & 7; return 1344 + u * 32 + 4 * c + vp; } // w4
  { int u = l - 200; return 1600 + u * 8 + c; }                                       // w5
}

// ---------------- counting sort of edges by edge_src ----------------
__global__ __launch_bounds__(256) void hist_kernel(
    const int* __restrict__ edge_src, int* __restrict__ hist, int E) {
  int e = blockIdx.x * 256 + threadIdx.x;
  if (e < E) atomicAdd(&hist[edge_src[e]], 1);
}

__global__ __launch_bounds__(256) void scan1_kernel(
    const int* __restrict__ hist, int* __restrict__ excl,
    int* __restrict__ bsum, int n) {
  __shared__ int s[256];
  int t = threadIdx.x, i = blockIdx.x * 256 + t;
  int v = (i < n) ? hist[i] : 0;
  s[t] = v;
  __syncthreads();
  #pragma unroll
  for (int off = 1; off < 256; off <<= 1) {
    int tv = (t >= off) ? s[t - off] : 0;
    __syncthreads();
    s[t] += tv;
    __syncthreads();
  }
  if (i < n) excl[i] = s[t] - v;
  if (t == 255) bsum[blockIdx.x] = s[255];
}

// merged scan2+scan3: each block locally scans the (<=256) block sums
__global__ __launch_bounds__(256) void scan23_kernel(
    const int* __restrict__ excl, const int* __restrict__ bsum,
    int* __restrict__ start, int* __restrict__ cur, int n, int nb) {
  __shared__ int s[256];
  int t = threadIdx.x;
  int v = (t < nb) ? bsum[t] : 0;
  s[t] = v;
  __syncthreads();
  #pragma unroll
  for (int off = 1; off < 256; off <<= 1) {
    int tv = (t >= off) ? s[t - off] : 0;
    __syncthreads();
    s[t] += tv;
    __syncthreads();
  }
  int add = (blockIdx.x > 0) ? s[blockIdx.x - 1] : 0;  // exclusive prefix of bsum
  int i = blockIdx.x * 256 + t;
  if (i < n) {
    int val = excl[i] + add;
    start[i] = val;
    cur[i] = val;
  }
}

// ---------------- weight prep (bf16 MFMA fragments) + hist zero ----------------
__global__ __launch_bounds__(256) void prep_kernel(
    const float* __restrict__ W2, const float* __restrict__ W1,
    const float* __restrict__ b2, unsigned short* __restrict__ W2p,
    unsigned short* __restrict__ W1p, float* __restrict__ b2p,
    int* __restrict__ hist, int nhist)
{
  int gid = blockIdx.x * 256 + threadIdx.x;
  if (gid < nhist) hist[gid] = 0;       // folded hist-zero (prep runs before hist)
  const int NW2 = NT_TOT * 3 * 64;
  const int NW1 = 18 * 64;
  if (gid < NW2) {
    int tile = gid >> 6, ln = gid & 63;
    int nt = tile / 3, s = tile - nt * 3;
    int J = nt * 16 + (ln & 15);
    int jo = perm_col(J);
    int kbase = s * 32 + ((ln >> 4) << 3);
    #pragma unroll
    for (int j = 0; j < 8; ++j)
      W2p[(size_t)gid * 8 + j] = f2bf(W2[(kbase + j) * WNUM + jo]);
  } else if (gid < NW2 + NW1) {
    int g = gid - NW2;
    int tile = g >> 6, ln = g & 63;
    int nt = tile / 3, s = tile - nt * 3;
    int col = nt * 16 + (ln & 15);
    int kbase = s * 32 + ((ln >> 4) << 3);
    #pragma unroll
    for (int j = 0; j < 8; ++j)
      W1p[(size_t)g * 8 + j] = f2bf(W1[(kbase + j) * HID + col]);
  } else if (gid < NW2 + NW1 + WNUM) {
    int J = gid - (NW2 + NW1);
    b2p[J] = b2[perm_col(J)];
  }
}

// K2: fused  h = relu(A@W1+b1) -> w = h@W2+b2 (MFMA, swapped operands:
//     C fragment = 4 consecutive COLUMNS at one edge -> b64 LDS writes)
//     -> dot2 TP (x in regs) -> bf16 store at sorted slot.
//     R17 structure: compute_chunk(ch+1) issued before TP(ch), one barrier-free
//     region per chunk so the COMPILER interleaves loads/MFMA/TP (explicit
//     sched_barrier fences regressed badly in R18 — do not reintroduce).
//     NOTE: (512,2) bound: 2-blocks/CU residency is LDS-bound; VGPR only needs
//     <=128. (512,4) caps VGPR at 64 and risks catastrophic spill (R7/R10).
__global__ __launch_bounds__(512, 2) void fused_mfma(
    const float* __restrict__ edge_attr, const unsigned short* __restrict__ W1p,
    const float* __restrict__ b1, const unsigned short* __restrict__ W2p,
    const float* __restrict__ b2p, const float* __restrict__ node_attr,
    const float* __restrict__ edge_sh, const int* __restrict__ edge_src,
    const int* __restrict__ edge_dst, int* __restrict__ cur,
    unsigned short* __restrict__ tpg)
{
  __shared__ __align__(16) unsigned short ws[2][EPB][212];  // 54.3 KB dbuf (bf16)
  __shared__ __align__(8) unsigned short x0h[EPB][32];      // x0, packed bf16
  __shared__ __align__(8) unsigned short x1h[EPB][3][8];    // x1[m][u], packed bf16
  __shared__ __align__(8) unsigned short dsuh[EPB][8];      // x1.sh1, packed bf16
  __shared__ __align__(8) unsigned short crsh[EPB][3][8];   // cross, packed bf16
  __shared__ float x1s[EPB][3][8];
  __shared__ float sh1s[EPB][3];
  __shared__ float s0s[EPB];
  __shared__ int   dsts[EPB];
  __shared__ int   poss[EPB];

  // prologue-only aliases inside the (not-yet-used) ws double buffer:
  unsigned short* As = (unsigned short*)ws;        // [EPB][APAD] bf16 edge_attr
  unsigned short* hB = As + EPB * APAD;            // [EPB][APAD] bf16 h

  const int tid = threadIdx.x;
  const int e0 = blockIdx.x * EPB;

  if (tid < EPB) {
    dsts[tid] = edge_dst[e0 + tid];
    s0s[tid] = edge_sh[(size_t)(e0 + tid) * 4];
    poss[tid] = atomicAdd(&cur[edge_src[e0 + tid]], 1);  // inline scatter
  }
  if (tid >= 128 && tid < 128 + EPB * 3) {
    int i = tid - 128, e = i / 3, m = i - e * 3;
    sh1s[e][m] = edge_sh[(size_t)(e0 + e) * 4 + 1 + m];
  }
  __syncthreads();

  // stage node_attr -> x arrays ; edge_attr -> As (bf16)
  for (int idx = tid; idx < EPB * NA_DIM; idx += 512) {
    int e = idx / NA_DIM, c = idx - e * NA_DIM;
    float v = node_attr[(size_t)dsts[e] * NA_DIM + c];
    if (c < 32) x0h[e][c] = f2bf_hw(v);
    else { int q = c - 32; x1s[e][q % 3][q / 3] = v; x1h[e][q % 3][q / 3] = f2bf_hw(v); }
  }
  for (int idx = tid; idx < EPB * (HID / 4); idx += 512) {
    int e = idx / (HID / 4), c4 = (idx - e * (HID / 4)) * 4;
    f32x4 v = *(const f32x4*)&edge_attr[(size_t)(e0 + e) * HID + c4];
    unsigned short* d = &As[e * APAD + c4];
    d[0] = f2bf_hw(v[0]); d[1] = f2bf_hw(v[1]); d[2] = f2bf_hw(v[2]); d[3] = f2bf_hw(v[3]);
  }
  __syncthreads();

  { // per-(e,u) derived quantities; 512 = 64*8 exact
    int e = tid >> 3, u = tid & 7;
    float a0 = x1s[e][0][u], a1 = x1s[e][1][u], a2 = x1s[e][2][u];
    float b0 = sh1s[e][0], b1v = sh1s[e][1], b2v = sh1s[e][2];
    dsuh[e][u] = f2bf_hw(a0 * b0 + a1 * b1v + a2 * b2v);
    crsh[e][0][u] = f2bf_hw(a1 * b2v - a2 * b1v);
    crsh[e][1][u] = f2bf_hw(a2 * b0 - a0 * b2v);
    crsh[e][2][u] = f2bf_hw(a0 * b1v - a1 * b0);
  }

  const int ln = tid & 63, wv = tid >> 6;
  const int c16 = ln & 15, q4 = (ln >> 4) << 2, k8 = (ln >> 4) << 3;

  // in-kernel GEMM1 (swapped): acc[r] = h[edge=c16][ntile*16+q4+r] -> b64 write
  #pragma unroll
  for (int t = 0; t < 3; ++t) {
    int tt_ = wv * 3 + t;
    int mtile = tt_ / 6, ntile = tt_ - mtile * 6;
    short8 aA[3];
    #pragma unroll
    for (int s = 0; s < 3; ++s)
      aA[s] = *(const short8*)&As[(mtile * 16 + c16) * APAD + s * 32 + k8];
    f32x4 acc = {0.f, 0.f, 0.f, 0.f};
    #pragma unroll
    for (int s = 0; s < 3; ++s) {
      short8 bfr = *(const short8*)(W1p + ((size_t)(ntile * 3 + s) * 64 + ln) * 8);
      acc = __builtin_amdgcn_mfma_f32_16x16x32_bf16(bfr, aA[s], acc, 0, 0, 0);
    }
    f32x4 bb = *(const f32x4*)&b1[ntile * 16 + q4];
    short4v o;
    #pragma unroll
    for (int r = 0; r < 4; ++r)
      o[r] = (short)f2bf_hw(fmaxf(acc[r] + bb[r], 0.f));
    *(short4v*)&hB[(mtile * 16 + c16) * APAD + ntile * 16 + q4] = o;
  }
  __syncthreads();

  short8 af[4][3];
  #pragma unroll
  for (int mt = 0; mt < 4; ++mt)
    #pragma unroll
    for (int s = 0; s < 3; ++s)
      af[mt][s] = *(const short8*)&hB[(mt * 16 + c16) * APAD + s * 32 + k8];
  __syncthreads();  // af in regs; ws free for chunk buffering

  // --- hoist per-edge TP operands into registers (reused all 8 chunks) ---
  const int e = tid >> 3, tt = tid & 7;
  uint2v x0r[8], aux0, aux1;   // role-dependent payload, ~20 VGPRs
  if (tt < 7) {
    #pragma unroll
    for (int i = 0; i < 8; ++i) x0r[i] = *(const uint2v*)&x0h[e][i * 4];
    if (tt < 4) {
      aux0 = *(const uint2v*)&dsuh[e][0];
      aux1 = *(const uint2v*)&dsuh[e][4];
    } else {
      aux0 = *(const uint2v*)&x1h[e][tt - 4][0];
      aux1 = *(const uint2v*)&x1h[e][tt - 4][4];
    }
  } else {
    #pragma unroll
    for (int m = 0; m < 3; ++m) {
      x0r[2 * m]     = *(const uint2v*)&crsh[e][m][0];
      x0r[2 * m + 1] = *(const uint2v*)&crsh[e][m][4];
    }
  }

  // chunk-invariant addressing (swapped layout: wave owns w-col tiles wv, wv+8)
  const int l0m = wv * 16 + q4;                  // tile0 col base (l), 4-aligned
  const int pc0m = (l0m & 96) | ((l0m + ((l0m >> 5) << 2)) & 31);  // w1 swizzle (4-run safe)
  const unsigned short* w2a = W2p + ((size_t)(wv * 3) * 64 + ln) * 8;          // tile0
  const unsigned short* w2b = W2p + ((size_t)((wv + 8) * 3) * 64 + ln) * 8;    // tile1
  const size_t CSTRIDE = (size_t)NTC * 3 * 64 * 8;   // W2p u16 per chunk
  const bool has1 = wv < (NTC - 8);

  // GEMM one 208-col chunk cc into LDS buffer wsd (MFMA + bias, b64 writes)
  auto compute_chunk = [&](int cc, unsigned short (*wsd)[212]) {
    const size_t cb = (size_t)cc * CSTRIDE;
    {
      f32x4 acc[4];
      #pragma unroll
      for (int et = 0; et < 4; ++et) acc[et] = (f32x4){0.f, 0.f, 0.f, 0.f};
      #pragma unroll
      for (int s = 0; s < 3; ++s) {
        short8 bfr = *(const short8*)(w2a + cb + (size_t)s * 64 * 8);
        #pragma unroll
        for (int et = 0; et < 4; ++et)
          acc[et] = __builtin_amdgcn_mfma_f32_16x16x32_bf16(bfr, af[et][s], acc[et], 0, 0, 0);
      }
      f32x4 bb = *(const f32x4*)&b2p[cc * CHW + l0m];
      #pragma unroll
      for (int et = 0; et < 4; ++et) {
        short4v o;
        #pragma unroll
        for (int r = 0; r < 4; ++r)
          o[r] = (short)f2bf_hw(acc[et][r] + bb[r]);
        *(short4v*)&wsd[et * 16 + c16][pc0m] = o;
      }
    }
    if (has1) {
      f32x4 acc[4];
      #pragma unroll
      for (int et = 0; et < 4; ++et) acc[et] = (f32x4){0.f, 0.f, 0.f, 0.f};
      #pragma unroll
      for (int s = 0; s < 3; ++s) {
        short8 bfr = *(const short8*)(w2b + cb + (size_t)s * 64 * 8);
        #pragma unroll
        for (int et = 0; et < 4; ++et)
          acc[et] = __builtin_amdgcn_mfma_f32_16x16x32_bf16(bfr, af[et][s], acc[et], 0, 0, 0);
      }
      f32x4 bb = *(const f32x4*)&b2p[cc * CHW + 128 + l0m];
      #pragma unroll
      for (int et = 0; et < 4; ++et) {
        short4v o;
        #pragma unroll
        for (int r = 0; r < 4; ++r)
          o[r] = (short)f2bf_hw(acc[et][r] + bb[r]);
        *(short4v*)&wsd[et * 16 + c16][128 + l0m] = o;
      }
    }
  };

  compute_chunk(0, ws[0]);
  __syncthreads();

  const float s0 = s0s[e];
  unsigned short* tpr = tpg + (size_t)poss[e] * OUT_DIM;   // sorted-position row

  for (int ch = 0; ch < NCH; ++ch) {
    if (ch < NCH - 1) compute_chunk(ch + 1, ws[(ch + 1) & 1]);  // overlaps TP below

    const unsigned short (*wsr)[212] = ws[ch & 1];
    if (tt < 4) {
      float c0 = 0.f, c1 = 0.f, c2 = 0.f, c3 = 0.f;   // 4 ILP chains
      #pragma unroll
      for (int u0 = 0; u0 < 32; u0 += 8) {
        int pu  = (u0 + (tt << 2)) & 31;       // swizzled LDS col of logical u0
        int pu2 = (u0 + 4 + (tt << 2)) & 31;
        uint2v wq  = *(const uint2v*)&wsr[e][(tt << 5) + pu];
        uint2v wq2 = *(const uint2v*)&wsr[e][(tt << 5) + pu2];
        uint2v xq  = x0r[u0 >> 2];
        uint2v xq2 = x0r[(u0 >> 2) + 1];
        DOT2(c0, wq[0], xq[0]);
        DOT2(c1, wq[1], xq[1]);
        DOT2(c2, wq2[0], xq2[0]);
        DOT2(c3, wq2[1], xq2[1]);
      }
      float d0 = 0.f, d1 = 0.f;
      {
        uint2v wq  = *(const uint2v*)&wsr[e][168 + (tt << 3)];
        uint2v wq2 = *(const uint2v*)&wsr[e][168 + (tt << 3) + 4];
        DOT2(d0, wq[0], aux0[0]);
        DOT2(d1, wq[1], aux0[1]);
        DOT2(d0, wq2[0], aux1[0]);
        DOT2(d1, wq2[1], aux1[1]);
      }
      float sum1 = (c0 + c1) + (c2 + c3);
      tpr[4 * ch + tt] = f2bf_hw(N0f * (s0 * sum1 + INV_S3 * (d0 + d1)));
    } else if (tt < 7) {
      const int m = tt - 4;
      float c0 = 0.f, c1 = 0.f, c2 = 0.f, c3 = 0.f;
      #pragma unroll
      for (int u0 = 0; u0 < 32; u0 += 8) {
        uint2v wq  = *(const uint2v*)&wsr[e][128 + u0];
        uint2v wq2 = *(const uint2v*)&wsr[e][128 + u0 + 4];
        uint2v xq  = x0r[u0 >> 2];
        uint2v xq2 = x0r[(u0 >> 2) + 1];
        DOT2(c0, wq[0], xq[0]);
        DOT2(c1, wq[1], xq[1]);
        DOT2(c2, wq2[0], xq2[0]);
        DOT2(c3, wq2[1], xq2[1]);
      }
      float d0 = 0.f, d1 = 0.f;
      {
        uint2v wq  = *(const uint2v*)&wsr[e][160];
        uint2v wq2 = *(const uint2v*)&wsr[e][164];
        DOT2(d0, wq[0], aux0[0]);
        DOT2(d1, wq[1], aux0[1]);
        DOT2(d0, wq2[0], aux1[0]);
        DOT2(d1, wq2[1], aux1[1]);
      }
      float sum1 = (c0 + c1) + (c2 + c3);
      tpr[32 + ch * 3 + m] = f2bf_hw(N0f * (sh1s[e][m] * sum1 + s0 * (d0 + d1)));
    } else {
      uint2v wq  = *(const uint2v*)&wsr[e][200];
      uint2v wq2 = *(const uint2v*)&wsr[e][204];
      #pragma unroll
      for (int m = 0; m < 3; ++m) {
        float d0 = 0.f, d1 = 0.f;
        DOT2(d0, wq[0], x0r[2 * m][0]);
        DOT2(d1, wq[1], x0r[2 * m][1]);
        DOT2(d0, wq2[0], x0r[2 * m + 1][0]);
        DOT2(d1, wq2[1], x0r[2 * m + 1][1]);
        tpr[56 + ch * 3 + m] = f2bf_hw(C_OUT1E * (d0 + d1));
      }
    }
    __syncthreads();  // ws[(ch+1)&1] complete, ws[ch&1] free for reuse
  }
}

// K3: per-node mean; tp rows are src-sorted (bf16) -> 2 bf16/thread streaming
__global__ __launch_bounds__(256) void gather_kernel(
    const unsigned short* __restrict__ tp, const int* __restrict__ start,
    const int* __restrict__ hist, float* __restrict__ out, int total2)
{
  int idx = blockIdx.x * 256 + threadIdx.x;
  if (idx >= total2) return;
  int node = idx / (OUT_DIM / 2), o2 = idx - node * (OUT_DIM / 2);
  int s = start[node], c = hist[node];
  float sa = 0.f, sb = 0.f;
  for (int i = 0; i < c; ++i) {
    unsigned v = *(const unsigned*)&tp[(size_t)(s + i) * OUT_DIM + o2 * 2];
    sa += bf2f((unsigned short)(v & 0xFFFF));
    sb += bf2f((unsigned short)(v >> 16));
  }
  float inv = 1.0f / (float)(c > 0 ? c : 1);
  out[(size_t)node * OUT_DIM + o2 * 2]     = sa * inv;
  out[(size_t)node * OUT_DIM + o2 * 2 + 1] = sb * inv;
}

extern "C" void kernel_launch(void* const* d_in, const int* in_sizes, int n_in,
                              void* d_out, int out_size, void* d_ws, size_t ws_size,
                              hipStream_t stream) {
  const float* node_attr = (const float*)d_in[0];
  const float* edge_attr = (const float*)d_in[1];
  const float* edge_sh   = (const float*)d_in[2];
  const float* W1        = (const float*)d_in[3];
  const float* b1        = (const float*)d_in[4];
  const float* W2        = (const float*)d_in[5];
  const float* b2        = (const float*)d_in[6];
  const int*   edge_src  = (const int*)d_in[7];
  const int*   edge_dst  = (const int*)d_in[8];
  float* out = (float*)d_out;

  const int E = in_sizes[7];
  const int N = in_sizes[0] / NA_DIM;

  char* wsb = (char*)d_ws;
  int*   hist  = (int*)(wsb + 0x000000);          // 40000 ints
  int*   excl  = (int*)(wsb + 0x040000);
  int*   start = (int*)(wsb + 0x080000);
  int*   cur   = (int*)(wsb + 0x0C0000);
  int*   bsum  = (int*)(wsb + 0x100000);          // 256 ints
  unsigned short* W2p = (unsigned short*)(wsb + 0x200000);   // 320 KB
  unsigned short* W1p = (unsigned short*)(wsb + 0x280000);
  float*          b2p = (float*)(wsb + 0x2C0000);
  unsigned short* tpg = (unsigned short*)(wsb + 0x1C00000);  // 19.2 MB (bf16)

  const int NB = (N + 255) / 256;  // 157

  // prep also zeros hist (grid sized to cover max(prep_total, N))
  const int prep_total = NT_TOT * 3 * 64 + 18 * 64 + WNUM;
  const int prep_grid = ((prep_total > N ? prep_total : N) + 255) / 256;
  prep_kernel<<<prep_grid, 256, 0, stream>>>(W2, W1, b2, W2p, W1p, b2p, hist, N);

  hist_kernel<<<(E + 255) / 256, 256, 0, stream>>>(edge_src, hist, E);
  scan1_kernel<<<NB, 256, 0, stream>>>(hist, excl, bsum, N);
  scan23_kernel<<<NB, 256, 0, stream>>>(excl, bsum, start, cur, N, NB);

  fused_mfma<<<E / EPB, 512, 0, stream>>>(edge_attr, W1p, b1, W2p, b2p,
                                          node_attr, edge_sh, edge_src, edge_dst,
                                          cur, tpg);
  gather_kernel<<<(N * (OUT_DIM / 2) + 255) / 256, 256, 0, stream>>>(
      tpg, start, hist, out, N * (OUT_DIM / 2));
}